// Round 14
// baseline (22769.624 us; speedup 1.0000x reference)
//
#include <hip/hip_runtime.h>
#include <math.h>
#include <stdint.h>
#include <limits.h>

#define VSZ 50257
#define ESZ 256
#define HSZ 1024
#define BSZ 64
#define TSZ 80
#define GC  4096            // 4*H gate columns
#define NFCB 786            // ceil(VSZ/64) FC col-blocks
#define NCAND (NFCB*5)      // 3930 candidates per batch row
#define NSLOT 13            // lstm part slots: A 0..8 (l0: 0..4, l1-rec: 5..8), B 9..12
#define NREF 16             // exact-refined candidates per batch row

typedef unsigned int u32;
typedef unsigned short u16;
typedef double f64x4 __attribute__((ext_vector_type(4)));
typedef float f32x4v __attribute__((ext_vector_type(4)));
typedef __bf16 bf16x8 __attribute__((ext_vector_type(8)));
union BFrag { u16 u[8]; bf16x8 v; };

__device__ __forceinline__ u16 f2bf(float f) {   // f32 -> bf16 RNE
  u32 x = __float_as_uint(f);
  return (u16)((x + 0x7FFFu + ((x >> 16) & 1u)) >> 16);
}
__device__ __forceinline__ float bf2f(u16 h) { return __uint_as_float(((u32)h) << 16); }

// ---------------- Threefry-2x32 (JAX exact) ----------------
__device__ __forceinline__ void tf2x32(u32 k0, u32 k1, u32& x0, u32& x1) {
  u32 ks2 = k0 ^ k1 ^ 0x1BD11BDAu;
  x0 += k0; x1 += k1;
#define RND(r) { x0 += x1; x1 = (x1 << r) | (x1 >> (32 - r)); x1 ^= x0; }
  RND(13) RND(15) RND(26) RND(6)
  x0 += k1; x1 += ks2 + 1u;
  RND(17) RND(29) RND(16) RND(24)
  x0 += ks2; x1 += k0 + 2u;
  RND(13) RND(15) RND(26) RND(6)
  x0 += k0; x1 += k1 + 3u;
  RND(17) RND(29) RND(16) RND(24)
  x0 += k1; x1 += ks2 + 4u;
  RND(13) RND(15) RND(26) RND(6)
  x0 += ks2; x1 += k0 + 5u;
#undef RND
}

__device__ __forceinline__ double dsig(double x) { return 0.5 + 0.5 * tanh(0.5 * x); }

// sorted-desc top5 insert; ties -> lower index first (matches lax.top_k)
__device__ __forceinline__ void ins5(double v, int i, double* tv, int* ti) {
  bool beat4 = (v > tv[4]) || (v == tv[4] && i < ti[4]);
  if (!beat4) return;
  tv[4] = v; ti[4] = i;
#pragma unroll
  for (int p = 4; p > 0; --p) {
    bool sw = (tv[p] > tv[p-1]) || (tv[p] == tv[p-1] && ti[p] < ti[p-1]);
    double a0 = sw ? tv[p] : tv[p-1]; double a1 = sw ? tv[p-1] : tv[p];
    tv[p-1] = a0; tv[p] = a1;
    int b0 = sw ? ti[p] : ti[p-1]; int b1 = sw ? ti[p-1] : ti[p];
    ti[p-1] = b0; ti[p] = b1;
  }
}

// exact integer reference D[m][n] for f64 probe: sum_k (4m+k+1)*(16k+n+1)
__device__ __forceinline__ double dref(int m, int n) {
  int s = 0;
#pragma unroll
  for (int k = 0; k < 4; ++k) s += (4*m + k + 1) * (16*k + n + 1);
  return (double)s;
}

// -------- MFMA layout probes: fb[0]=f64 conv (0..3), fb[2]=bf16 maps ok --------
__global__ __launch_bounds__(64) void k_probe(int* __restrict__ fbp) {
  int l = threadIdx.x;
  int lane16 = l & 15, sub = l >> 4;
  {
    double av = (double)(4 * lane16 + sub + 1);     // A[m=lane16][k=sub]
    double bv = (double)(16 * sub + lane16 + 1);    // B[k=sub][n=lane16]
    f64x4 acc = {0., 0., 0., 0.};
    acc = __builtin_amdgcn_mfma_f64_16x16x4f64(av, bv, acc, 0, 0, 0);
    bool o0 = true, o1 = true, o2 = true, o3 = true;
#pragma unroll
    for (int j = 0; j < 4; ++j) {
      double d = acc[j];
      o0 = o0 && (d == dref(4 * sub + j, lane16));
      o1 = o1 && (d == dref(lane16, 4 * sub + j));
      o2 = o2 && (d == dref(sub + 4 * j, lane16));
      o3 = o3 && (d == dref(lane16, sub + 4 * j));
    }
    int a0 = __all(o0), a1 = __all(o1), a2 = __all(o2), a3 = __all(o3);
    if (l == 0) { fbp[0] = a0 ? 0 : a1 ? 1 : a2 ? 2 : 3; fbp[1] = 0; }
  }
  {
    BFrag fa, fbv;
#pragma unroll
    for (int i = 0; i < 8; ++i) {
      int k = sub * 8 + i;
      fa.u[i]  = f2bf((float)((lane16 * 5 + k * 3) % 63 + 1));
      fbv.u[i] = f2bf((float)((k * 7 + lane16 * 11) % 61 + 1));
    }
    f32x4v c = {0.f, 0.f, 0.f, 0.f};
    c = __builtin_amdgcn_mfma_f32_16x16x32_bf16(fa.v, fbv.v, c, 0, 0, 0);
    bool okb = true;
#pragma unroll
    for (int j = 0; j < 4; ++j) {
      int mm = sub * 4 + j, nn = lane16;
      int ref = 0;
      for (int k = 0; k < 32; ++k) ref += ((mm*5 + k*3) % 63 + 1) * ((k*7 + nn*11) % 61 + 1);
      okb = okb && (c[j] == (float)ref);
    }
    int allb = __all(okb);
    if (l == 0) fbp[2] = allb;
  }
}

// -------- one-time: fc_w [k][v] f32 -> whT [v][k] bf16 (tiled transpose) --------
__global__ __launch_bounds__(256) void k_wconv(const float* __restrict__ W, u16* __restrict__ whT) {
  __shared__ u16 tile[64][65];
  int vb = blockIdx.x * 64, kb = blockIdx.y * 64;
  int tid = threadIdx.x;
#pragma unroll
  for (int i = 0; i < 16; ++i) {
    int r = i * 4 + (tid >> 6), c = tid & 63;       // r = k-offset, c = v-offset
    int v = vb + c;
    tile[c][r] = (v < VSZ) ? f2bf(W[(size_t)(kb + r) * VSZ + v]) : (u16)0;
  }
  __syncthreads();
#pragma unroll
  for (int i = 0; i < 16; ++i) {
    int r = i * 4 + (tid >> 6), c = tid & 63;       // r = v-offset, c = k-offset
    int v = vb + r;
    if (v < VSZ) whT[(size_t)v * 1024 + kb + c] = tile[r][c];
  }
}

// -------- fused RNG: gumbel[t][m] for t<80, m<320 --------
__global__ __launch_bounds__(256) void k_rng(double* __restrict__ gum) {
  int idx = blockIdx.x * 256 + threadIdx.x;
  if (idx >= TSZ * 320) return;
  int t = idx / 320, m = idx % 320;
  u32 a0 = 0u, a1 = (u32)t;
  tf2x32(0u, 42u, a0, a1);
  u32 x0 = 0u, x1 = (u32)m;
  tf2x32(a0, a1, x0, x1);
  u32 bits = x0 ^ x1;
  const float TINY = 1.17549435082228750797e-38f;  // 2^-126
  float f = __uint_as_float((bits >> 9) | 0x3f800000u) - 1.0f;
  float u = f + TINY;
  u = fmaxf(TINY, u);
  gum[idx] = -log(-log((double)u));
}

// -------- time encode stage 1 --------
__global__ __launch_bounds__(256) void k_time1(const float* __restrict__ hours, const float* __restrict__ w1,
                                               const float* __restrict__ bb1, double* __restrict__ tp1T) {
  int idx = blockIdx.x * 256 + threadIdx.x;  // 64*1024
  int b = idx & 63, hcol = idx >> 6;
  const float TPO = (float)(2.0 * 3.14159265358979323846 / 24.0);
  float af = hours[b] * TPO;
  double a = (double)af;
  double sv = sin(a), cv = cos(a);
  double vv = tanh(sv * (double)w1[hcol] + cv * (double)w1[HSZ + hcol] + (double)bb1[hcol]);
  tp1T[(size_t)hcol * 64 + b] = vv;
}

// -------- simple split-K gemm (prologue-only, runs once) --------
__global__ __launch_bounds__(256) void k_gemm_simple(const double* __restrict__ XTa, const float* __restrict__ Wa,
                                                     int Ka, int Sa, double* __restrict__ part) {
  int j = blockIdx.x * 256 + threadIdx.x;
  if (j >= GC) return;
  int s = blockIdx.y;
  int kc = Ka / Sa, k0 = s * kc;
  double acc[BSZ];
#pragma unroll
  for (int b = 0; b < BSZ; ++b) acc[b] = 0.0;
  const float* wp = Wa + (size_t)k0 * GC + j;
  const double* xp = XTa + (size_t)k0 * 64;
  for (int k = 0; k < kc; ++k) {
    double wv = (double)wp[0]; wp += GC;
#pragma unroll
    for (int b = 0; b < BSZ; ++b) acc[b] = fma(wv, xp[b], acc[b]);
    xp += 64;
  }
  double* o = part + ((size_t)s * 64) * GC + j;
#pragma unroll
  for (int b = 0; b < BSZ; ++b) o[(size_t)b * GC] = acc[b];
}

// -------- time encode stage 2 reduce --------
__global__ __launch_bounds__(256) void k_t2r(const double* __restrict__ part, const float* __restrict__ b2,
                                             double* __restrict__ h0T, double* __restrict__ c0,
                                             double* __restrict__ h1T, double* __restrict__ c1) {
  int b = blockIdx.y;
  int j = blockIdx.x * 256 + threadIdx.x;
  double acc = (double)b2[j];
  for (int s = 0; s < 8; ++s) acc += part[((size_t)s * 64 + b) * GC + j];
  int l = j >> 11, half = (j >> 10) & 1, hcol = j & 1023;
  if (half == 0) (l ? h1T : h0T)[(size_t)hcol * 64 + b] = acc;
  else           (l ? c1 : c0)[(size_t)b * HSZ + hcol] = acc;
}

// -------- LSTM gemm via f64 VECTOR pipe: C=4 x B=4, x via LDS broadcast --------
// thread: vg = tid&15 (cols vg+16i), bg = tid>>4 (b = bg*4+j). K=256/slice. part[s][b][col].
__global__ __launch_bounds__(256, 4) void k_lstm_vec(const double* __restrict__ x0, const float* __restrict__ W0,
                                                     const double* __restrict__ x1, const float* __restrict__ W1,
                                                     const double* __restrict__ x2, const float* __restrict__ W2,
                                                     int s1, int s2, double* __restrict__ part) {
  __shared__ double xs[64 * 64];   // 32KB x-chunk [k][b]
  int tid = threadIdx.x;
  int vg = tid & 15, bg = tid >> 4;
  int colbase = blockIdx.x * 64;
  int s = blockIdx.y;
  const double* XT; const float* W; int k0;
  if (s < s1)      { XT = x0; W = W0; k0 = s * 256; }
  else if (s < s2) { XT = x1; W = W1; k0 = (s - s1) * 256; }
  else             { XT = x2; W = W2; k0 = (s - s2) * 256; }
  double acc[4][4];
#pragma unroll
  for (int ci = 0; ci < 4; ++ci)
#pragma unroll
    for (int j = 0; j < 4; ++j) acc[ci][j] = 0.0;
  const float* wp = W + (size_t)k0 * GC + colbase + vg;
  float wb[4][4];
#pragma unroll
  for (int u = 0; u < 4; ++u) {
    wb[u][0] = wp[0]; wb[u][1] = wp[16]; wb[u][2] = wp[32]; wb[u][3] = wp[48];
    wp += GC;
  }
  for (int ch = 0; ch < 4; ++ch) {
    __syncthreads();
    const double2* src = (const double2*)(XT + (size_t)(k0 + ch * 64) * 64);
    double2* dst = (double2*)xs;
    for (int i = tid; i < 2048; i += 256) dst[i] = src[i];
    __syncthreads();
    for (int g = 0; g < 16; ++g) {
#pragma unroll
      for (int u = 0; u < 4; ++u) {
        int step = ch * 64 + g * 4 + u;
        float n0 = 0.f, n1 = 0.f, n2 = 0.f, n3 = 0.f;
        if (step + 4 < 256) { n0 = wp[0]; n1 = wp[16]; n2 = wp[32]; n3 = wp[48]; }
        wp += GC;
        // x broadcast: 16 vg-lanes share addresses (conflict-free)
        const double2* xp = (const double2*)(xs + (g * 4 + u) * 64 + (bg << 2));
        double2 xa = xp[0], xb2 = xp[1];
        double w0 = (double)wb[u][0], w1 = (double)wb[u][1];
        double w2 = (double)wb[u][2], w3 = (double)wb[u][3];
        acc[0][0] = fma(w0, xa.x, acc[0][0]);  acc[0][1] = fma(w0, xa.y, acc[0][1]);
        acc[0][2] = fma(w0, xb2.x, acc[0][2]); acc[0][3] = fma(w0, xb2.y, acc[0][3]);
        acc[1][0] = fma(w1, xa.x, acc[1][0]);  acc[1][1] = fma(w1, xa.y, acc[1][1]);
        acc[1][2] = fma(w1, xb2.x, acc[1][2]); acc[1][3] = fma(w1, xb2.y, acc[1][3]);
        acc[2][0] = fma(w2, xa.x, acc[2][0]);  acc[2][1] = fma(w2, xa.y, acc[2][1]);
        acc[2][2] = fma(w2, xb2.x, acc[2][2]); acc[2][3] = fma(w2, xb2.y, acc[2][3]);
        acc[3][0] = fma(w3, xa.x, acc[3][0]);  acc[3][1] = fma(w3, xa.y, acc[3][1]);
        acc[3][2] = fma(w3, xb2.x, acc[3][2]); acc[3][3] = fma(w3, xb2.y, acc[3][3]);
        wb[u][0] = n0; wb[u][1] = n1; wb[u][2] = n2; wb[u][3] = n3;
      }
    }
  }
#pragma unroll
  for (int ci = 0; ci < 4; ++ci)
#pragma unroll
    for (int j = 0; j < 4; ++j)
      part[((size_t)s * 64 + bg * 4 + j) * GC + colbase + vg + 16 * ci] = acc[ci][j];
}

// -------- LSTM cell; optional bf16 emission of h in FC chunk layout [ch][b][k&127] --------
__global__ __launch_bounds__(256) void k_cell(const double* __restrict__ part, int sBeg, int S,
                                              const float* __restrict__ bias,
                                              double* __restrict__ c, double* __restrict__ hT,
                                              int emit, u16* __restrict__ xh) {
  int b = blockIdx.y;
  int hcol = blockIdx.x * 256 + threadIdx.x;
  double gi = (double)bias[hcol];
  double gf = (double)bias[1024 + hcol];
  double gg = (double)bias[2048 + hcol];
  double go = (double)bias[3072 + hcol];
#pragma unroll 4
  for (int s = sBeg; s < sBeg + S; ++s) {
    const double* p = part + ((size_t)s * 64 + b) * GC;
    gi += p[hcol]; gf += p[1024 + hcol]; gg += p[2048 + hcol]; go += p[3072 + hcol];
  }
  size_t ci = (size_t)b * HSZ + hcol;
  double cn = dsig(gf) * c[ci] + dsig(gi) * tanh(gg);
  double hn = dsig(go) * tanh(cn);
  c[ci] = cn;
  hT[(size_t)hcol * 64 + b] = hn;
  if (emit)
    xh[(size_t)(hcol >> 7) * 8192 + (size_t)b * 128 + (hcol & 127)] = f2bf((float)hn);
}

// -------- merged FC: bf16-MFMA fast path OR f64-MFMA fallback, one launch --------
__global__ __launch_bounds__(256, 4) void k_fc(const u16* __restrict__ xhg, const u16* __restrict__ whT,
                                               const double* __restrict__ h1T, const float* __restrict__ W,
                                               const float* __restrict__ fcb,
                                               double* __restrict__ candV, int* __restrict__ candI,
                                               const int* __restrict__ fbp, int force) {
  __shared__ double xs[64 * 64];     // staging, then transpose buffer
  int tid = threadIdx.x;
  int l = tid & 63, wv = tid >> 6;
  int sub = l >> 4, lane16 = l & 15;
  int vbase = blockIdx.x * 64;
  int colA = min(vbase + wv * 16 + lane16, VSZ - 1);
  bool bf = (!force) && (fbp[2] != 0);
  if (bf) {
    // ---- bf16 path (R13-validated): preconverted whT, 1 MFMA/frag ----
    u16* lx = (u16*)xs;
    const u16* wrow = whT + (size_t)colA * 1024;
    f32x4v acc0 = {0,0,0,0}, acc1 = {0,0,0,0}, acc2 = {0,0,0,0}, acc3 = {0,0,0,0};
    for (int ch = 0; ch < 8; ++ch) {
      bf16x8 wh0 = *(const bf16x8*)(wrow + ch * 128 + 0 * 32 + sub * 8);
      bf16x8 wh1 = *(const bf16x8*)(wrow + ch * 128 + 1 * 32 + sub * 8);
      bf16x8 wh2 = *(const bf16x8*)(wrow + ch * 128 + 2 * 32 + sub * 8);
      bf16x8 wh3 = *(const bf16x8*)(wrow + ch * 128 + 3 * 32 + sub * 8);
      __syncthreads();
      {
        const uint4* sg = (const uint4*)(xhg + (size_t)ch * 8192);
        uint4* dl = (uint4*)lx;
#pragma unroll
        for (int i = 0; i < 4; ++i) {
          int u = tid + i * 256;               // unit = b*16 + g (g = k'/8)
          int bswz = u >> 4, g = u & 15;
          dl[(bswz << 4) | (g ^ (bswz & 7))] = sg[u];  // XOR-swizzle
        }
      }
      __syncthreads();
#pragma unroll
      for (int kt = 0; kt < 4; ++kt) {
        bf16x8 whv = (kt == 0) ? wh0 : (kt == 1) ? wh1 : (kt == 2) ? wh2 : wh3;
#define BT_STEP(BT, ACC) {                                                              \
          int bb = BT * 16 + lane16;                                                    \
          const bf16x8* bp2 = (const bf16x8*)lx + ((bb << 4) | ((kt * 4 + sub) ^ (bb & 7))); \
          ACC = __builtin_amdgcn_mfma_f32_16x16x32_bf16(whv, *bp2, ACC, 0, 0, 0); }
        BT_STEP(0, acc0)
        BT_STEP(1, acc1)
        BT_STEP(2, acc2)
        BT_STEP(3, acc3)
#undef BT_STEP
      }
    }
    __syncthreads();
    // D: m=(l>>4)*4+j (vocab), n=lane16 (+bt*16) (batch)
#pragma unroll
    for (int j = 0; j < 4; ++j) {
      int vl = wv * 16 + sub * 4 + j;
      int v = vbase + vl;
      bool okv = (v < VSZ);
      double bi = okv ? (double)fcb[min(v, VSZ - 1)] : 0.0;
      int b0i = lane16, b1i = 16 + lane16, b2i = 32 + lane16, b3i = 48 + lane16;
      xs[b0i * 64 + ((vl + b0i) & 63)] = okv ? ((double)acc0[j] + bi) / 0.75 : -INFINITY;
      xs[b1i * 64 + ((vl + b1i) & 63)] = okv ? ((double)acc1[j] + bi) / 0.75 : -INFINITY;
      xs[b2i * 64 + ((vl + b2i) & 63)] = okv ? ((double)acc2[j] + bi) / 0.75 : -INFINITY;
      xs[b3i * 64 + ((vl + b3i) & 63)] = okv ? ((double)acc3[j] + bi) / 0.75 : -INFINITY;
    }
  } else {
    // ---- f64 MFMA fallback (R8 HW-validated) ----
    int conv = fbp[0] & 3;
    f64x4 a0 = {0.,0.,0.,0.}, a1 = {0.,0.,0.,0.}, a2 = {0.,0.,0.,0.}, a3 = {0.,0.,0.,0.};
    const float* wp = W + (size_t)sub * VSZ + colA;
    float ab[8];
#pragma unroll
    for (int u = 0; u < 8; ++u) { ab[u] = wp[0]; wp += (size_t)4 * VSZ; }
    for (int ch = 0; ch < 16; ++ch) {
      __syncthreads();
      const double2* src = (const double2*)(h1T + (size_t)ch * 64 * 64);
      double2* dst = (double2*)xs;
      for (int i = tid; i < 2048; i += 256) dst[i] = src[i];
      __syncthreads();
#pragma unroll
      for (int g = 0; g < 2; ++g) {
#pragma unroll
        for (int u = 0; u < 8; ++u) {
          int ks = g * 8 + u;
          int step = ch * 16 + ks;
          float nv = 0.f;
          if (step + 8 < 256) nv = wp[0];
          wp += (size_t)4 * VSZ;
          double av = (double)ab[u];
          const double* bp = xs + (ks * 4 + sub) * 64 + lane16;
          double b0 = bp[0], b1 = bp[16], b2 = bp[32], b3 = bp[48];
          a0 = __builtin_amdgcn_mfma_f64_16x16x4f64(av, b0, a0, 0, 0, 0);
          a1 = __builtin_amdgcn_mfma_f64_16x16x4f64(av, b1, a1, 0, 0, 0);
          a2 = __builtin_amdgcn_mfma_f64_16x16x4f64(av, b2, a2, 0, 0, 0);
          a3 = __builtin_amdgcn_mfma_f64_16x16x4f64(av, b3, a3, 0, 0, 0);
          ab[u] = nv;
        }
      }
    }
    __syncthreads();
#pragma unroll
    for (int j = 0; j < 4; ++j) {
      int m = (conv == 0) ? sub * 4 + j : (conv == 2) ? sub + 4 * j : lane16;
      int n = (conv == 0) ? lane16 : (conv == 2) ? lane16 : ((conv == 1) ? sub * 4 + j : sub + 4 * j);
      int vl = wv * 16 + m;
      int v = vbase + vl;
      bool okv = (v < VSZ);
      double bi = okv ? (double)fcb[min(v, VSZ - 1)] : 0.0;
      int b0i = n, b1i = 16 + n, b2i = 32 + n, b3i = 48 + n;
      xs[b0i * 64 + ((vl + b0i) & 63)] = okv ? (a0[j] + bi) / 0.75 : -INFINITY;
      xs[b1i * 64 + ((vl + b1i) & 63)] = okv ? (a1[j] + bi) / 0.75 : -INFINITY;
      xs[b2i * 64 + ((vl + b2i) & 63)] = okv ? (a2[j] + bi) / 0.75 : -INFINITY;
      xs[b3i * 64 + ((vl + b3i) & 63)] = okv ? (a3[j] + bi) / 0.75 : -INFINITY;
    }
  }
  __syncthreads();
  if (tid < 64) {
    int b = tid;
    double tv[5]; int ti[5];
#pragma unroll
    for (int p = 0; p < 5; ++p) { tv[p] = -INFINITY; ti[p] = INT_MAX; }
    for (int vl2 = 0; vl2 < 64; ++vl2)
      ins5(xs[b * 64 + ((vl2 + b) & 63)], vbase + vl2, tv, ti);
#pragma unroll
    for (int r = 0; r < 5; ++r) {
      candV[(size_t)b * NCAND + blockIdx.x * 5 + r] = tv[r];
      candI[(size_t)b * NCAND + blockIdx.x * 5 + r] = ti[r];
    }
  }
}

// -------- refine + finalize: approx top-16 (wave-local, 2 barriers) -> exact f64 -> outputs --------
__global__ __launch_bounds__(256) void k_rfin(const double* __restrict__ candV, const int* __restrict__ candI,
                                              const float* __restrict__ W, const float* __restrict__ fcb,
                                              const double* __restrict__ h1T,
                                              const double* __restrict__ gum, int t,
                                              const float* __restrict__ embed,
                                              float* __restrict__ out, double* __restrict__ xt0) {
  __shared__ double exS[NREF];
  __shared__ float mv64[64]; __shared__ int mi64[64];
  __shared__ int cidxS[NREF];
  int b = blockIdx.x, tid = threadIdx.x;
  int l = tid & 63, wvd = tid >> 6;
  // per-lane candidate slice (registers)
  float v[16]; int ix[16];
#pragma unroll
  for (int q = 0; q < 16; ++q) {
    int e = tid + q * 256;
    if (e < NCAND) {
      v[q] = (float)candV[(size_t)b * NCAND + e];
      ix[q] = candI[(size_t)b * NCAND + e];
    } else { v[q] = -INFINITY; ix[q] = INT_MAX; }
  }
  // wave-local top-16 (no block barriers)
#pragma unroll
  for (int r = 0; r < 16; ++r) {
    float bv = -INFINITY; int bi = INT_MAX; int bq = 0;
#pragma unroll
    for (int q = 0; q < 16; ++q)
      if (v[q] > bv || (v[q] == bv && ix[q] < bi)) { bv = v[q]; bi = ix[q]; bq = q; }
    float wv2 = bv; int wi = bi;
#pragma unroll
    for (int off = 1; off < 64; off <<= 1) {
      float ov = __shfl_xor(wv2, off, 64);
      int oi = __shfl_xor(wi, off, 64);
      if (ov > wv2 || (ov == wv2 && oi < wi)) { wv2 = ov; wi = oi; }
    }
    if (bv == wv2 && bi == wi) { v[bq] = -INFINITY; ix[bq] = INT_MAX; }  // unique idx -> one lane
    if (l == 0) { mv64[wvd * 16 + r] = wv2; mi64[wvd * 16 + r] = wi; }
  }
  __syncthreads();
  // wave 0 merges 64 -> top-16
  if (wvd == 0) {
    float cv = mv64[l]; int ci2 = mi64[l];
#pragma unroll
    for (int r = 0; r < NREF; ++r) {
      float bv = cv; int bi = ci2;
#pragma unroll
      for (int off = 1; off < 64; off <<= 1) {
        float ov = __shfl_xor(bv, off, 64);
        int oi = __shfl_xor(bi, off, 64);
        if (ov > bv || (ov == bv && oi < bi)) { bv = ov; bi = oi; }
      }
      if (cv == bv && ci2 == bi) { cv = -INFINITY; ci2 = INT_MAX; }
      if (l == 0) cidxS[r] = bi;
    }
  }
  __syncthreads();
  // exact dots: wave wvd handles candidates wvd, wvd+4, wvd+8, wvd+12
#pragma unroll
  for (int rr = 0; rr < 4; ++rr) {
    int c = wvd + rr * 4;
    int vc = cidxS[c];
    double p = 0.0;
#pragma unroll
    for (int i = 0; i < 16; ++i) {
      int k = i * 64 + l;
      p = fma((double)W[(size_t)k * VSZ + vc], h1T[(size_t)k * 64 + b], p);
    }
#pragma unroll
    for (int off = 1; off < 64; off <<= 1) p += __shfl_xor(p, off, 64);
    if (l == 0) exS[c] = (p + (double)fcb[vc]) / 0.75;
  }
  __syncthreads();
  double tv[5]; int ti[5];
#pragma unroll
  for (int p = 0; p < 5; ++p) { tv[p] = -INFINITY; ti[p] = INT_MAX; }
#pragma unroll
  for (int c = 0; c < NREF; ++c) ins5(exS[c], cidxS[c], tv, ti);
  const double* g = gum + (size_t)t * 320 + b * 5;
  double bestv = tv[0] + g[0]; int best = 0;
#pragma unroll
  for (int k2 = 1; k2 < 5; ++k2) { double vv2 = tv[k2] + g[k2]; if (vv2 > bestv) { bestv = vv2; best = k2; } }
  int nxt = ti[best];
  if (tid == 0) {
    out[b * TSZ + t] = (float)nxt;
    double m = tv[0];
    double exx[5]; double s = 0.0;
#pragma unroll
    for (int k2 = 0; k2 < 5; ++k2) { exx[k2] = exp(tv[k2] - m); s += exx[k2]; }
    float* po = out + BSZ * TSZ + ((size_t)b * TSZ + t) * 5;
#pragma unroll
    for (int k2 = 0; k2 < 5; ++k2) po[k2] = (float)(exx[k2] / s);
  }
  xt0[(size_t)tid * 64 + b] = (double)embed[(size_t)nxt * ESZ + tid];
}

// -------- initial embedding of SOS --------
__global__ __launch_bounds__(256) void k_emb0(const float* __restrict__ embed, const int* __restrict__ sos,
                                              double* __restrict__ xt0) {
  int idx = blockIdx.x * 256 + threadIdx.x;
  int b = idx & 63, k = idx >> 6;
  xt0[(size_t)k * 64 + b] = (double)embed[(size_t)sos[0] * ESZ + k];
}

extern "C" void kernel_launch(void* const* d_in, const int* in_sizes, int n_in,
                              void* d_out, int out_size, void* d_ws, size_t ws_size,
                              hipStream_t stream) {
  const float* hours = (const float*)d_in[0];
  const float* tp_w1 = (const float*)d_in[1];
  const float* tp_b1 = (const float*)d_in[2];
  const float* tp_w2 = (const float*)d_in[3];
  const float* tp_b2 = (const float*)d_in[4];
  const float* embed = (const float*)d_in[5];
  const float* w_ih0 = (const float*)d_in[6];
  const float* w_hh0 = (const float*)d_in[7];
  const float* b0    = (const float*)d_in[8];
  const float* w_ih1 = (const float*)d_in[9];
  const float* w_hh1 = (const float*)d_in[10];
  const float* b1    = (const float*)d_in[11];
  const float* fc_w  = (const float*)d_in[12];
  const float* fc_b  = (const float*)d_in[13];
  const int*   sos   = (const int*)d_in[14];
  float* out = (float*)d_out;

  char* w = (char*)d_ws;
  double* part = (double*)w;  w += (size_t)NSLOT * 64 * GC * 8;   // 27.3 MB lstm partials
  double* xt0  = (double*)w;  w += (size_t)ESZ * 64 * 8;
  double* h0T  = (double*)w;  w += (size_t)HSZ * 64 * 8;
  double* h1T  = (double*)w;  w += (size_t)HSZ * 64 * 8;
  double* c0   = (double*)w;  w += (size_t)BSZ * HSZ * 8;
  double* c1   = (double*)w;  w += (size_t)BSZ * HSZ * 8;
  double* tp1T = (double*)w;  w += (size_t)HSZ * 64 * 8;
  double* gum  = (double*)w;  w += (size_t)TSZ * 320 * 8;
  double* candV = (double*)w; w += (size_t)BSZ * NCAND * 8;       // 2.01 MB, b-major
  int*    candI = (int*)w;    w += (size_t)BSZ * NCAND * 4;       // 1.01 MB
  int*    fbuf  = (int*)w;    w += 64;                            // [0]=f64 conv, [2]=bf16 ok
  u16*    xhg   = (u16*)w;    w += (size_t)HSZ * 64 * 2;          // 128 KB bf16 h1 (chunk layout)
  u16*    whT   = (u16*)w;    w += (size_t)VSZ * 1024 * 2;        // 102.9 MB transposed bf16 fc_w
  size_t need = (size_t)(w - (char*)d_ws);
  int useBF = (ws_size >= need) ? 1 : 0;

  k_probe<<<dim3(1), dim3(64), 0, stream>>>(fbuf);
  k_rng<<<dim3(100), dim3(256), 0, stream>>>(gum);
  k_time1<<<dim3(256), dim3(256), 0, stream>>>(hours, tp_w1, tp_b1, tp1T);
  k_gemm_simple<<<dim3(16, 8), dim3(256), 0, stream>>>(tp1T, tp_w2, 1024, 8, part);
  k_t2r<<<dim3(16, 64), dim3(256), 0, stream>>>(part, tp_b2, h0T, c0, h1T, c1);
  k_emb0<<<dim3(64), dim3(256), 0, stream>>>(embed, sos, xt0);
  if (useBF)
    k_wconv<<<dim3(786, 16), dim3(256), 0, stream>>>(fc_w, whT);

  double* part9 = part + (size_t)9 * 64 * GC;
  for (int t = 0; t < TSZ; ++t) {
    // A: slot 0 = xt0*w_ih0 (K=256), slots 1-4 = h0*w_hh0, slots 5-8 = h1*w_hh1
    k_lstm_vec<<<dim3(64, 9), dim3(256), 0, stream>>>(xt0, w_ih0, h0T, w_hh0, h1T, w_hh1, 1, 5, part);
    // layer-0 cell: slots 0..4
    k_cell<<<dim3(4, 64), dim3(256), 0, stream>>>(part, 0, 5, b0, c0, h0T, 0, xhg);
    // B: slices 0-3 = h0n*w_ih1 -> slots 9..12
    k_lstm_vec<<<dim3(64, 4), dim3(256), 0, stream>>>(h0T, w_ih1, h0T, w_ih1, h0T, w_ih1, 4, 4, part9);
    // layer-1 cell: slots 5..12 = h1*w_hh1 (5-8) + h0n*w_ih1 (9-12)
    k_cell<<<dim3(4, 64), dim3(256), 0, stream>>>(part, 5, 8, b1, c1, h1T, 1, xhg);
    k_fc<<<dim3(NFCB), dim3(256), 0, stream>>>(xhg, whT, h1T, fc_w, fc_b, candV, candI, fbuf, useBF ? 0 : 1);
    k_rfin<<<dim3(64), dim3(256), 0, stream>>>(candV, candI, fc_w, fc_b, h1T, gum, t, embed, out, xt0);
  }
}

// Round 15
// 19469.965 us; speedup vs baseline: 1.1695x; 1.1695x over previous
//
#include <hip/hip_runtime.h>
#include <math.h>
#include <stdint.h>
#include <limits.h>

#define VSZ 50257
#define ESZ 256
#define HSZ 1024
#define BSZ 64
#define TSZ 80
#define GC  4096            // 4*H gate columns
#define NFCB 786            // ceil(VSZ/64) FC col-blocks
#define NCAND (NFCB*5)      // 3930 candidates per batch row
#define NSLOT 26            // lstm part slots: A 0..17 (l0: 0..9, l1-rec: 10..17), B 18..25
#define NREF 16             // exact-refined candidates per batch row

typedef unsigned int u32;
typedef unsigned short u16;
typedef double f64x4 __attribute__((ext_vector_type(4)));
typedef float f32x4v __attribute__((ext_vector_type(4)));
typedef __bf16 bf16x8 __attribute__((ext_vector_type(8)));
union BFrag { u16 u[8]; bf16x8 v; };

__device__ __forceinline__ u16 f2bf(float f) {   // f32 -> bf16 RNE
  u32 x = __float_as_uint(f);
  return (u16)((x + 0x7FFFu + ((x >> 16) & 1u)) >> 16);
}
__device__ __forceinline__ float bf2f(u16 h) { return __uint_as_float(((u32)h) << 16); }

// ---------------- Threefry-2x32 (JAX exact) ----------------
__device__ __forceinline__ void tf2x32(u32 k0, u32 k1, u32& x0, u32& x1) {
  u32 ks2 = k0 ^ k1 ^ 0x1BD11BDAu;
  x0 += k0; x1 += k1;
#define RND(r) { x0 += x1; x1 = (x1 << r) | (x1 >> (32 - r)); x1 ^= x0; }
  RND(13) RND(15) RND(26) RND(6)
  x0 += k1; x1 += ks2 + 1u;
  RND(17) RND(29) RND(16) RND(24)
  x0 += ks2; x1 += k0 + 2u;
  RND(13) RND(15) RND(26) RND(6)
  x0 += k0; x1 += k1 + 3u;
  RND(17) RND(29) RND(16) RND(24)
  x0 += k1; x1 += ks2 + 4u;
  RND(13) RND(15) RND(26) RND(6)
  x0 += ks2; x1 += k0 + 5u;
#undef RND
}

__device__ __forceinline__ double dsig(double x) { return 0.5 + 0.5 * tanh(0.5 * x); }

// sorted-desc top5 insert; ties -> lower index first (matches lax.top_k)
__device__ __forceinline__ void ins5(double v, int i, double* tv, int* ti) {
  bool beat4 = (v > tv[4]) || (v == tv[4] && i < ti[4]);
  if (!beat4) return;
  tv[4] = v; ti[4] = i;
#pragma unroll
  for (int p = 4; p > 0; --p) {
    bool sw = (tv[p] > tv[p-1]) || (tv[p] == tv[p-1] && ti[p] < ti[p-1]);
    double a0 = sw ? tv[p] : tv[p-1]; double a1 = sw ? tv[p-1] : tv[p];
    tv[p-1] = a0; tv[p] = a1;
    int b0 = sw ? ti[p] : ti[p-1]; int b1 = sw ? ti[p-1] : ti[p];
    ti[p-1] = b0; ti[p] = b1;
  }
}

// exact integer reference D[m][n] for f64 probe: sum_k (4m+k+1)*(16k+n+1)
__device__ __forceinline__ double dref(int m, int n) {
  int s = 0;
#pragma unroll
  for (int k = 0; k < 4; ++k) s += (4*m + k + 1) * (16*k + n + 1);
  return (double)s;
}

// -------- MFMA layout probes: fb[0]=f64 conv (0..3), fb[2]=bf16 maps ok --------
__global__ __launch_bounds__(64) void k_probe(int* __restrict__ fbp) {
  int l = threadIdx.x;
  int lane16 = l & 15, sub = l >> 4;
  {
    double av = (double)(4 * lane16 + sub + 1);     // A[m=lane16][k=sub]
    double bv = (double)(16 * sub + lane16 + 1);    // B[k=sub][n=lane16]
    f64x4 acc = {0., 0., 0., 0.};
    acc = __builtin_amdgcn_mfma_f64_16x16x4f64(av, bv, acc, 0, 0, 0);
    bool o0 = true, o1 = true, o2 = true, o3 = true;
#pragma unroll
    for (int j = 0; j < 4; ++j) {
      double d = acc[j];
      o0 = o0 && (d == dref(4 * sub + j, lane16));
      o1 = o1 && (d == dref(lane16, 4 * sub + j));
      o2 = o2 && (d == dref(sub + 4 * j, lane16));
      o3 = o3 && (d == dref(lane16, sub + 4 * j));
    }
    int a0 = __all(o0), a1 = __all(o1), a2 = __all(o2), a3 = __all(o3);
    if (l == 0) { fbp[0] = a0 ? 0 : a1 ? 1 : a2 ? 2 : 3; fbp[1] = 0; }
  }
  {
    BFrag fa, fbv;
#pragma unroll
    for (int i = 0; i < 8; ++i) {
      int k = sub * 8 + i;
      fa.u[i]  = f2bf((float)((lane16 * 5 + k * 3) % 63 + 1));
      fbv.u[i] = f2bf((float)((k * 7 + lane16 * 11) % 61 + 1));
    }
    f32x4v c = {0.f, 0.f, 0.f, 0.f};
    c = __builtin_amdgcn_mfma_f32_16x16x32_bf16(fa.v, fbv.v, c, 0, 0, 0);
    bool okb = true;
#pragma unroll
    for (int j = 0; j < 4; ++j) {
      int mm = sub * 4 + j, nn = lane16;
      int ref = 0;
      for (int k = 0; k < 32; ++k) ref += ((mm*5 + k*3) % 63 + 1) * ((k*7 + nn*11) % 61 + 1);
      okb = okb && (c[j] == (float)ref);
    }
    int allb = __all(okb);
    if (l == 0) fbp[2] = allb;
  }
}

// -------- one-time: fc_w [k][v] f32 -> whT [v][k] bf16 (tiled transpose) --------
__global__ __launch_bounds__(256) void k_wconv(const float* __restrict__ W, u16* __restrict__ whT) {
  __shared__ u16 tile[64][65];
  int vb = blockIdx.x * 64, kb = blockIdx.y * 64;
  int tid = threadIdx.x;
#pragma unroll
  for (int i = 0; i < 16; ++i) {
    int r = i * 4 + (tid >> 6), c = tid & 63;       // r = k-offset, c = v-offset
    int v = vb + c;
    tile[c][r] = (v < VSZ) ? f2bf(W[(size_t)(kb + r) * VSZ + v]) : (u16)0;
  }
  __syncthreads();
#pragma unroll
  for (int i = 0; i < 16; ++i) {
    int r = i * 4 + (tid >> 6), c = tid & 63;       // r = v-offset, c = k-offset
    int v = vb + r;
    if (v < VSZ) whT[(size_t)v * 1024 + kb + c] = tile[r][c];
  }
}

// -------- fused RNG: gumbel[t][m] for t<80, m<320 --------
__global__ __launch_bounds__(256) void k_rng(double* __restrict__ gum) {
  int idx = blockIdx.x * 256 + threadIdx.x;
  if (idx >= TSZ * 320) return;
  int t = idx / 320, m = idx % 320;
  u32 a0 = 0u, a1 = (u32)t;
  tf2x32(0u, 42u, a0, a1);
  u32 x0 = 0u, x1 = (u32)m;
  tf2x32(a0, a1, x0, x1);
  u32 bits = x0 ^ x1;
  const float TINY = 1.17549435082228750797e-38f;  // 2^-126
  float f = __uint_as_float((bits >> 9) | 0x3f800000u) - 1.0f;
  float u = f + TINY;
  u = fmaxf(TINY, u);
  gum[idx] = -log(-log((double)u));
}

// -------- time encode stage 1 --------
__global__ __launch_bounds__(256) void k_time1(const float* __restrict__ hours, const float* __restrict__ w1,
                                               const float* __restrict__ bb1, double* __restrict__ tp1T) {
  int idx = blockIdx.x * 256 + threadIdx.x;  // 64*1024
  int b = idx & 63, hcol = idx >> 6;
  const float TPO = (float)(2.0 * 3.14159265358979323846 / 24.0);
  float af = hours[b] * TPO;
  double a = (double)af;
  double sv = sin(a), cv = cos(a);
  double vv = tanh(sv * (double)w1[hcol] + cv * (double)w1[HSZ + hcol] + (double)bb1[hcol]);
  tp1T[(size_t)hcol * 64 + b] = vv;
}

// -------- simple split-K gemm (prologue-only, runs once) --------
__global__ __launch_bounds__(256) void k_gemm_simple(const double* __restrict__ XTa, const float* __restrict__ Wa,
                                                     int Ka, int Sa, double* __restrict__ part) {
  int j = blockIdx.x * 256 + threadIdx.x;
  if (j >= GC) return;
  int s = blockIdx.y;
  int kc = Ka / Sa, k0 = s * kc;
  double acc[BSZ];
#pragma unroll
  for (int b = 0; b < BSZ; ++b) acc[b] = 0.0;
  const float* wp = Wa + (size_t)k0 * GC + j;
  const double* xp = XTa + (size_t)k0 * 64;
  for (int k = 0; k < kc; ++k) {
    double wv = (double)wp[0]; wp += GC;
#pragma unroll
    for (int b = 0; b < BSZ; ++b) acc[b] = fma(wv, xp[b], acc[b]);
    xp += 64;
  }
  double* o = part + ((size_t)s * 64) * GC + j;
#pragma unroll
  for (int b = 0; b < BSZ; ++b) o[(size_t)b * GC] = acc[b];
}

// -------- time encode stage 2 reduce --------
__global__ __launch_bounds__(256) void k_t2r(const double* __restrict__ part, const float* __restrict__ b2,
                                             double* __restrict__ h0T, double* __restrict__ c0,
                                             double* __restrict__ h1T, double* __restrict__ c1) {
  int b = blockIdx.y;
  int j = blockIdx.x * 256 + threadIdx.x;
  double acc = (double)b2[j];
  for (int s = 0; s < 8; ++s) acc += part[((size_t)s * 64 + b) * GC + j];
  int l = j >> 11, half = (j >> 10) & 1, hcol = j & 1023;
  if (half == 0) (l ? h1T : h0T)[(size_t)hcol * 64 + b] = acc;
  else           (l ? c1 : c0)[(size_t)b * HSZ + hcol] = acc;
}

// -------- LSTM gemm via f64 MFMA (R8/R11 HW-validated); K=128/slice; part[s][b][col] --------
__global__ __launch_bounds__(256, 4) void k_lstm_mfma(const double* __restrict__ x0, const float* __restrict__ W0,
                                                      const double* __restrict__ x1, const float* __restrict__ W1,
                                                      const double* __restrict__ x2, const float* __restrict__ W2,
                                                      int s1, int s2, double* __restrict__ part,
                                                      const int* __restrict__ fbp) {
  int conv = fbp[0] & 3;
  __shared__ double xs[64 * 64];   // 32KB x-chunk [k][b]
  int tid = threadIdx.x;
  int l = tid & 63, wv = tid >> 6;
  int sub = l >> 4, lane16 = l & 15;
  int colbase = blockIdx.x * 64;
  int s = blockIdx.y;
  const double* XT; const float* W; int k0;
  if (s < s1)      { XT = x0; W = W0; k0 = s * 128; }
  else if (s < s2) { XT = x1; W = W1; k0 = (s - s1) * 128; }
  else             { XT = x2; W = W2; k0 = (s - s2) * 128; }
  int colA = colbase + wv * 16 + lane16;
  f64x4 a0 = {0.,0.,0.,0.}, a1 = {0.,0.,0.,0.}, a2 = {0.,0.,0.,0.}, a3 = {0.,0.,0.,0.};
  const float* wp = W + (size_t)(k0 + sub) * GC + colA;
  float ab[8];
#pragma unroll
  for (int u = 0; u < 8; ++u) { ab[u] = wp[0]; wp += (size_t)4 * GC; }
  for (int ch = 0; ch < 2; ++ch) {
    __syncthreads();
    const double2* src = (const double2*)(XT + (size_t)(k0 + ch * 64) * 64);
    double2* dst = (double2*)xs;
    for (int i = tid; i < 2048; i += 256) dst[i] = src[i];
    __syncthreads();
#pragma unroll
    for (int g = 0; g < 2; ++g) {
#pragma unroll
      for (int u = 0; u < 8; ++u) {
        int ks = g * 8 + u;
        int step = ch * 16 + ks;
        float nv = 0.f;
        if (step + 8 < 32) nv = wp[0];
        wp += (size_t)4 * GC;
        double av = (double)ab[u];
        const double* bp = xs + (ks * 4 + sub) * 64 + lane16;
        double b0 = bp[0], b1 = bp[16], b2 = bp[32], b3 = bp[48];
        a0 = __builtin_amdgcn_mfma_f64_16x16x4f64(av, b0, a0, 0, 0, 0);
        a1 = __builtin_amdgcn_mfma_f64_16x16x4f64(av, b1, a1, 0, 0, 0);
        a2 = __builtin_amdgcn_mfma_f64_16x16x4f64(av, b2, a2, 0, 0, 0);
        a3 = __builtin_amdgcn_mfma_f64_16x16x4f64(av, b3, a3, 0, 0, 0);
        ab[u] = nv;
      }
    }
  }
#pragma unroll
  for (int j = 0; j < 4; ++j) {
    int m = (conv == 0) ? sub * 4 + j : (conv == 2) ? sub + 4 * j : lane16;
    int n = (conv == 0) ? lane16 : (conv == 2) ? lane16 : ((conv == 1) ? sub * 4 + j : sub + 4 * j);
    size_t base = ((size_t)s * 64 + n) * GC + colbase + wv * 16 + m;
    part[base]                   = a0[j];
    part[base + (size_t)16 * GC] = a1[j];
    part[base + (size_t)32 * GC] = a2[j];
    part[base + (size_t)48 * GC] = a3[j];
  }
}

// -------- LSTM cell; optional bf16 emission of h in FC chunk layout [ch][b][k&127] --------
__global__ __launch_bounds__(256) void k_cell(const double* __restrict__ part, int sBeg, int S,
                                              const float* __restrict__ bias,
                                              double* __restrict__ c, double* __restrict__ hT,
                                              int emit, u16* __restrict__ xh) {
  int b = blockIdx.y;
  int hcol = blockIdx.x * 256 + threadIdx.x;
  double gi = (double)bias[hcol];
  double gf = (double)bias[1024 + hcol];
  double gg = (double)bias[2048 + hcol];
  double go = (double)bias[3072 + hcol];
#pragma unroll 4
  for (int s = sBeg; s < sBeg + S; ++s) {
    const double* p = part + ((size_t)s * 64 + b) * GC;
    gi += p[hcol]; gf += p[1024 + hcol]; gg += p[2048 + hcol]; go += p[3072 + hcol];
  }
  size_t ci = (size_t)b * HSZ + hcol;
  double cn = dsig(gf) * c[ci] + dsig(gi) * tanh(gg);
  double hn = dsig(go) * tanh(cn);
  c[ci] = cn;
  hT[(size_t)hcol * 64 + b] = hn;
  if (emit)
    xh[(size_t)(hcol >> 7) * 8192 + (size_t)b * 128 + (hcol & 127)] = f2bf((float)hn);
}

// -------- FC approx via bf16 MFMA (preconverted whT) + per-block top5 --------
__global__ __launch_bounds__(256, 4) void k_fcbf(const u16* __restrict__ xhg, const u16* __restrict__ whT,
                                                 const float* __restrict__ fcb,
                                                 double* __restrict__ candV, int* __restrict__ candI,
                                                 const int* __restrict__ fbp) {
  if (fbp[2] == 0) return;
  __shared__ double xs[64 * 64];     // phase 1: 16KB swizzled xh tile; phase 2: transpose buffer
  u16* lx = (u16*)xs;
  int tid = threadIdx.x;
  int l = tid & 63, wv = tid >> 6;
  int sub = l >> 4, lane16 = l & 15;
  int vbase = blockIdx.x * 64;
  int colA = min(vbase + wv * 16 + lane16, VSZ - 1);
  const u16* wrow = whT + (size_t)colA * 1024;
  f32x4v acc0 = {0,0,0,0}, acc1 = {0,0,0,0}, acc2 = {0,0,0,0}, acc3 = {0,0,0,0};
  for (int ch = 0; ch < 8; ++ch) {
    bf16x8 wh0 = *(const bf16x8*)(wrow + ch * 128 + 0 * 32 + sub * 8);
    bf16x8 wh1 = *(const bf16x8*)(wrow + ch * 128 + 1 * 32 + sub * 8);
    bf16x8 wh2 = *(const bf16x8*)(wrow + ch * 128 + 2 * 32 + sub * 8);
    bf16x8 wh3 = *(const bf16x8*)(wrow + ch * 128 + 3 * 32 + sub * 8);
    __syncthreads();
    {
      const uint4* sg = (const uint4*)(xhg + (size_t)ch * 8192);
      uint4* dl = (uint4*)lx;
#pragma unroll
      for (int i = 0; i < 4; ++i) {
        int u = tid + i * 256;               // unit = b*16 + g (g = k'/8)
        int bswz = u >> 4, g = u & 15;
        dl[(bswz << 4) | (g ^ (bswz & 7))] = sg[u];  // XOR-swizzle kills bank conflicts
      }
    }
    __syncthreads();
#pragma unroll
    for (int kt = 0; kt < 4; ++kt) {
      bf16x8 whv = (kt == 0) ? wh0 : (kt == 1) ? wh1 : (kt == 2) ? wh2 : wh3;
#define BT_STEP(BT, ACC) {                                                              \
        int bb = BT * 16 + lane16;                                                      \
        const bf16x8* bp2 = (const bf16x8*)lx + ((bb << 4) | ((kt * 4 + sub) ^ (bb & 7))); \
        ACC = __builtin_amdgcn_mfma_f32_16x16x32_bf16(whv, *bp2, ACC, 0, 0, 0); }
      BT_STEP(0, acc0)
      BT_STEP(1, acc1)
      BT_STEP(2, acc2)
      BT_STEP(3, acc3)
#undef BT_STEP
    }
  }
  __syncthreads();   // staging reads done; reuse xs as transpose buffer
  // D: m=(l>>4)*4+j (vocab), n=lane16 (+bt*16) (batch)  [probe-verified, R11/R13-validated]
#pragma unroll
  for (int j = 0; j < 4; ++j) {
    int vl = wv * 16 + sub * 4 + j;
    int v = vbase + vl;
    bool okv = (v < VSZ);
    double bi = okv ? (double)fcb[min(v, VSZ - 1)] : 0.0;
    int b0i = lane16, b1i = 16 + lane16, b2i = 32 + lane16, b3i = 48 + lane16;
    xs[b0i * 64 + ((vl + b0i) & 63)] = okv ? ((double)acc0[j] + bi) / 0.75 : -INFINITY;
    xs[b1i * 64 + ((vl + b1i) & 63)] = okv ? ((double)acc1[j] + bi) / 0.75 : -INFINITY;
    xs[b2i * 64 + ((vl + b2i) & 63)] = okv ? ((double)acc2[j] + bi) / 0.75 : -INFINITY;
    xs[b3i * 64 + ((vl + b3i) & 63)] = okv ? ((double)acc3[j] + bi) / 0.75 : -INFINITY;
  }
  __syncthreads();
  if (tid < 64) {
    int b = tid;
    double tv[5]; int ti[5];
#pragma unroll
    for (int p = 0; p < 5; ++p) { tv[p] = -INFINITY; ti[p] = INT_MAX; }
    for (int vl2 = 0; vl2 < 64; ++vl2)
      ins5(xs[b * 64 + ((vl2 + b) & 63)], vbase + vl2, tv, ti);
#pragma unroll
    for (int r = 0; r < 5; ++r) {
      candV[(size_t)b * NCAND + blockIdx.x * 5 + r] = tv[r];
      candI[(size_t)b * NCAND + blockIdx.x * 5 + r] = ti[r];
    }
  }
}

// -------- FC via f64 MFMA (fallback: bf16 probe fail OR ws too small) --------
__global__ __launch_bounds__(256, 4) void k_fcf64(const double* __restrict__ h1T, const float* __restrict__ W,
                                                  const float* __restrict__ fcb,
                                                  double* __restrict__ candV, int* __restrict__ candI,
                                                  const int* __restrict__ fbp, int force) {
  if (!force && fbp[2] != 0) return;
  int conv = fbp[0] & 3;
  __shared__ double xs[64 * 64];
  int tid = threadIdx.x;
  int l = tid & 63, wv = tid >> 6;
  int sub = l >> 4, lane16 = l & 15;
  int vbase = blockIdx.x * 64;
  int colA = min(vbase + wv * 16 + lane16, VSZ - 1);
  f64x4 a0 = {0.,0.,0.,0.}, a1 = {0.,0.,0.,0.}, a2 = {0.,0.,0.,0.}, a3 = {0.,0.,0.,0.};
  const float* wp = W + (size_t)sub * VSZ + colA;
  float ab[8];
#pragma unroll
  for (int u = 0; u < 8; ++u) { ab[u] = wp[0]; wp += (size_t)4 * VSZ; }
  for (int ch = 0; ch < 16; ++ch) {
    __syncthreads();
    const double2* src = (const double2*)(h1T + (size_t)ch * 64 * 64);
    double2* dst = (double2*)xs;
    for (int i = tid; i < 2048; i += 256) dst[i] = src[i];
    __syncthreads();
#pragma unroll
    for (int g = 0; g < 2; ++g) {
#pragma unroll
      for (int u = 0; u < 8; ++u) {
        int ks = g * 8 + u;
        int step = ch * 16 + ks;
        float nv = 0.f;
        if (step + 8 < 256) nv = wp[0];
        wp += (size_t)4 * VSZ;
        double av = (double)ab[u];
        const double* bp = xs + (ks * 4 + sub) * 64 + lane16;
        double b0 = bp[0], b1 = bp[16], b2 = bp[32], b3 = bp[48];
        a0 = __builtin_amdgcn_mfma_f64_16x16x4f64(av, b0, a0, 0, 0, 0);
        a1 = __builtin_amdgcn_mfma_f64_16x16x4f64(av, b1, a1, 0, 0, 0);
        a2 = __builtin_amdgcn_mfma_f64_16x16x4f64(av, b2, a2, 0, 0, 0);
        a3 = __builtin_amdgcn_mfma_f64_16x16x4f64(av, b3, a3, 0, 0, 0);
        ab[u] = nv;
      }
    }
  }
  __syncthreads();
#pragma unroll
  for (int j = 0; j < 4; ++j) {
    int m = (conv == 0) ? sub * 4 + j : (conv == 2) ? sub + 4 * j : lane16;
    int n = (conv == 0) ? lane16 : (conv == 2) ? lane16 : ((conv == 1) ? sub * 4 + j : sub + 4 * j);
    int vl = wv * 16 + m;
    int v = vbase + vl;
    bool okv = (v < VSZ);
    double bi = okv ? (double)fcb[min(v, VSZ - 1)] : 0.0;
    int b0i = n, b1i = 16 + n, b2i = 32 + n, b3i = 48 + n;
    xs[b0i * 64 + ((vl + b0i) & 63)] = okv ? (a0[j] + bi) / 0.75 : -INFINITY;
    xs[b1i * 64 + ((vl + b1i) & 63)] = okv ? (a1[j] + bi) / 0.75 : -INFINITY;
    xs[b2i * 64 + ((vl + b2i) & 63)] = okv ? (a2[j] + bi) / 0.75 : -INFINITY;
    xs[b3i * 64 + ((vl + b3i) & 63)] = okv ? (a3[j] + bi) / 0.75 : -INFINITY;
  }
  __syncthreads();
  if (tid < 64) {
    int b = tid;
    double tv[5]; int ti[5];
#pragma unroll
    for (int p = 0; p < 5; ++p) { tv[p] = -INFINITY; ti[p] = INT_MAX; }
    for (int vl2 = 0; vl2 < 64; ++vl2)
      ins5(xs[b * 64 + ((vl2 + b) & 63)], vbase + vl2, tv, ti);
#pragma unroll
    for (int r = 0; r < 5; ++r) {
      candV[(size_t)b * NCAND + blockIdx.x * 5 + r] = tv[r];
      candI[(size_t)b * NCAND + blockIdx.x * 5 + r] = ti[r];
    }
  }
}

// -------- refine + finalize: approx top-16 -> exact f64 logits -> top5/gumbel/probs --------
__global__ __launch_bounds__(256) void k_rfin(const double* __restrict__ candV, const int* __restrict__ candI,
                                              const float* __restrict__ W, const float* __restrict__ fcb,
                                              const double* __restrict__ h1T,
                                              const double* __restrict__ gum, int t,
                                              const float* __restrict__ embed,
                                              float* __restrict__ out, double* __restrict__ xt0) {
  __shared__ float sv[NCAND];
  __shared__ int   si[NCAND];
  __shared__ double exS[NREF];
  __shared__ float wvv[4]; __shared__ int wvi[4]; __shared__ int wvs[4];
  int b = blockIdx.x, tid = threadIdx.x;
  int l = tid & 63, wvd = tid >> 6;
  for (int e = tid; e < NCAND; e += 256) {
    sv[e] = (float)candV[(size_t)b * NCAND + e];
    si[e] = candI[(size_t)b * NCAND + e];
  }
  __syncthreads();
  int cidx[NREF];
#pragma unroll
  for (int r = 0; r < NREF; ++r) {
    float bv = -INFINITY; int bi = INT_MAX, bs = 0;
    for (int e = tid; e < NCAND; e += 256) {
      float v = sv[e]; int i2 = si[e];
      if (v > bv || (v == bv && i2 < bi)) { bv = v; bi = i2; bs = e; }
    }
#pragma unroll
    for (int off = 1; off < 64; off <<= 1) {
      float ov = __shfl_xor(bv, off, 64);
      int oi = __shfl_xor(bi, off, 64);
      int os = __shfl_xor(bs, off, 64);
      if (ov > bv || (ov == bv && oi < bi)) { bv = ov; bi = oi; bs = os; }
    }
    if (l == 0) { wvv[wvd] = bv; wvi[wvd] = bi; wvs[wvd] = bs; }
    __syncthreads();
    float fv = wvv[0]; int fi = wvi[0], fs = wvs[0];
#pragma unroll
    for (int q = 1; q < 4; ++q) {
      float ov = wvv[q]; int oi = wvi[q], os = wvs[q];
      if (ov > fv || (ov == fv && oi < fi)) { fv = ov; fi = oi; fs = os; }
    }
    cidx[r] = fi;
    __syncthreads();
    if (tid == 0) sv[fs] = -INFINITY;
    __syncthreads();
  }
  // exact dots: wave wvd handles candidates wvd, wvd+4, wvd+8, wvd+12 (no block barriers)
#pragma unroll
  for (int rr = 0; rr < 4; ++rr) {
    int c = wvd + rr * 4;
    int vc = cidx[c];
    double p = 0.0;
#pragma unroll
    for (int i = 0; i < 16; ++i) {
      int k = i * 64 + l;
      p = fma((double)W[(size_t)k * VSZ + vc], h1T[(size_t)k * 64 + b], p);
    }
#pragma unroll
    for (int off = 1; off < 64; off <<= 1) p += __shfl_xor(p, off, 64);
    if (l == 0) exS[c] = (p + (double)fcb[vc]) / 0.75;
  }
  __syncthreads();
  double tv[5]; int ti[5];
#pragma unroll
  for (int p = 0; p < 5; ++p) { tv[p] = -INFINITY; ti[p] = INT_MAX; }
#pragma unroll
  for (int c = 0; c < NREF; ++c) ins5(exS[c], cidx[c], tv, ti);
  const double* g = gum + (size_t)t * 320 + b * 5;
  double bestv = tv[0] + g[0]; int best = 0;
#pragma unroll
  for (int k2 = 1; k2 < 5; ++k2) { double vv2 = tv[k2] + g[k2]; if (vv2 > bestv) { bestv = vv2; best = k2; } }
  int nxt = ti[best];
  if (tid == 0) {
    out[b * TSZ + t] = (float)nxt;
    double m = tv[0];
    double exx[5]; double s = 0.0;
#pragma unroll
    for (int k2 = 0; k2 < 5; ++k2) { exx[k2] = exp(tv[k2] - m); s += exx[k2]; }
    float* po = out + BSZ * TSZ + ((size_t)b * TSZ + t) * 5;
#pragma unroll
    for (int k2 = 0; k2 < 5; ++k2) po[k2] = (float)(exx[k2] / s);
  }
  xt0[(size_t)tid * 64 + b] = (double)embed[(size_t)nxt * ESZ + tid];
}

// -------- initial embedding of SOS --------
__global__ __launch_bounds__(256) void k_emb0(const float* __restrict__ embed, const int* __restrict__ sos,
                                              double* __restrict__ xt0) {
  int idx = blockIdx.x * 256 + threadIdx.x;
  int b = idx & 63, k = idx >> 6;
  xt0[(size_t)k * 64 + b] = (double)embed[(size_t)sos[0] * ESZ + k];
}

extern "C" void kernel_launch(void* const* d_in, const int* in_sizes, int n_in,
                              void* d_out, int out_size, void* d_ws, size_t ws_size,
                              hipStream_t stream) {
  const float* hours = (const float*)d_in[0];
  const float* tp_w1 = (const float*)d_in[1];
  const float* tp_b1 = (const float*)d_in[2];
  const float* tp_w2 = (const float*)d_in[3];
  const float* tp_b2 = (const float*)d_in[4];
  const float* embed = (const float*)d_in[5];
  const float* w_ih0 = (const float*)d_in[6];
  const float* w_hh0 = (const float*)d_in[7];
  const float* b0    = (const float*)d_in[8];
  const float* w_ih1 = (const float*)d_in[9];
  const float* w_hh1 = (const float*)d_in[10];
  const float* b1    = (const float*)d_in[11];
  const float* fc_w  = (const float*)d_in[12];
  const float* fc_b  = (const float*)d_in[13];
  const int*   sos   = (const int*)d_in[14];
  float* out = (float*)d_out;

  char* w = (char*)d_ws;
  double* part = (double*)w;  w += (size_t)NSLOT * 64 * GC * 8;   // 54.5 MB lstm partials
  double* xt0  = (double*)w;  w += (size_t)ESZ * 64 * 8;
  double* h0T  = (double*)w;  w += (size_t)HSZ * 64 * 8;
  double* h1T  = (double*)w;  w += (size_t)HSZ * 64 * 8;
  double* c0   = (double*)w;  w += (size_t)BSZ * HSZ * 8;
  double* c1   = (double*)w;  w += (size_t)BSZ * HSZ * 8;
  double* tp1T = (double*)w;  w += (size_t)HSZ * 64 * 8;
  double* gum  = (double*)w;  w += (size_t)TSZ * 320 * 8;
  double* candV = (double*)w; w += (size_t)BSZ * NCAND * 8;       // 2.01 MB, b-major
  int*    candI = (int*)w;    w += (size_t)BSZ * NCAND * 4;       // 1.01 MB
  int*    fbuf  = (int*)w;    w += 64;                            // [0]=f64 conv, [2]=bf16 ok
  u16*    xhg   = (u16*)w;    w += (size_t)HSZ * 64 * 2;          // 128 KB bf16 h1 (chunk layout)
  u16*    whT   = (u16*)w;    w += (size_t)VSZ * 1024 * 2;        // 102.9 MB transposed bf16 fc_w
  size_t need = (size_t)(w - (char*)d_ws);
  int useBF = (ws_size >= need) ? 1 : 0;

  k_probe<<<dim3(1), dim3(64), 0, stream>>>(fbuf);
  k_rng<<<dim3(100), dim3(256), 0, stream>>>(gum);
  k_time1<<<dim3(256), dim3(256), 0, stream>>>(hours, tp_w1, tp_b1, tp1T);
  k_gemm_simple<<<dim3(16, 8), dim3(256), 0, stream>>>(tp1T, tp_w2, 1024, 8, part);
  k_t2r<<<dim3(16, 64), dim3(256), 0, stream>>>(part, tp_b2, h0T, c0, h1T, c1);
  k_emb0<<<dim3(64), dim3(256), 0, stream>>>(embed, sos, xt0);
  if (useBF)
    k_wconv<<<dim3(786, 16), dim3(256), 0, stream>>>(fc_w, whT);

  double* part18 = part + (size_t)18 * 64 * GC;
  for (int t = 0; t < TSZ; ++t) {
    // A: slots 0-1 = xt0*w_ih0 (K=128 x2), slots 2-9 = h0*w_hh0, slots 10-17 = h1*w_hh1
    k_lstm_mfma<<<dim3(64, 18), dim3(256), 0, stream>>>(xt0, w_ih0, h0T, w_hh0, h1T, w_hh1, 2, 10, part, fbuf);
    // layer-0 cell: slots 0..9
    k_cell<<<dim3(4, 64), dim3(256), 0, stream>>>(part, 0, 10, b0, c0, h0T, 0, xhg);
    // B: slices 0-7 = h0n*w_ih1 -> slots 18..25
    k_lstm_mfma<<<dim3(64, 8), dim3(256), 0, stream>>>(h0T, w_ih1, h0T, w_ih1, h0T, w_ih1, 8, 8, part18, fbuf);
    // layer-1 cell: slots 10..25 = h1*w_hh1 (10-17) + h0n*w_ih1 (18-25)
    k_cell<<<dim3(4, 64), dim3(256), 0, stream>>>(part, 10, 16, b1, c1, h1T, 1, xhg);
    if (useBF)
      k_fcbf<<<dim3(NFCB), dim3(256), 0, stream>>>(xhg, whT, fc_b, candV, candI, fbuf);
    k_fcf64<<<dim3(NFCB), dim3(256), 0, stream>>>(h1T, fc_w, fc_b, candV, candI, fbuf, useBF ? 0 : 1);
    k_rfin<<<dim3(64), dim3(256), 0, stream>>>(candV, candI, fc_w, fc_b, h1T, gum, t, embed, out, xt0);
  }
}

// Round 16
// 18975.063 us; speedup vs baseline: 1.2000x; 1.0261x over previous
//
#include <hip/hip_runtime.h>
#include <math.h>
#include <stdint.h>
#include <limits.h>

#define VSZ 50257
#define ESZ 256
#define HSZ 1024
#define BSZ 64
#define TSZ 80
#define GC  4096            // 4*H gate columns
#define NFCB 786            // ceil(VSZ/64) FC col-blocks
#define NCAND (NFCB*5)      // 3930 candidates per batch row
#define NSLOT 13            // lstm part slots: A 0..8 (l0: 0..4, l1-rec: 5..8), B 9..12
#define NREF 16             // exact-refined candidates per batch row

typedef unsigned int u32;
typedef unsigned short u16;
typedef double f64x4 __attribute__((ext_vector_type(4)));
typedef float f32x4v __attribute__((ext_vector_type(4)));
typedef __bf16 bf16x8 __attribute__((ext_vector_type(8)));
union BFrag { u16 u[8]; bf16x8 v; };

__device__ __forceinline__ u16 f2bf(float f) {   // f32 -> bf16 RNE
  u32 x = __float_as_uint(f);
  return (u16)((x + 0x7FFFu + ((x >> 16) & 1u)) >> 16);
}
__device__ __forceinline__ float bf2f(u16 h) { return __uint_as_float(((u32)h) << 16); }

// ---------------- Threefry-2x32 (JAX exact) ----------------
__device__ __forceinline__ void tf2x32(u32 k0, u32 k1, u32& x0, u32& x1) {
  u32 ks2 = k0 ^ k1 ^ 0x1BD11BDAu;
  x0 += k0; x1 += k1;
#define RND(r) { x0 += x1; x1 = (x1 << r) | (x1 >> (32 - r)); x1 ^= x0; }
  RND(13) RND(15) RND(26) RND(6)
  x0 += k1; x1 += ks2 + 1u;
  RND(17) RND(29) RND(16) RND(24)
  x0 += ks2; x1 += k0 + 2u;
  RND(13) RND(15) RND(26) RND(6)
  x0 += k0; x1 += k1 + 3u;
  RND(17) RND(29) RND(16) RND(24)
  x0 += k1; x1 += ks2 + 4u;
  RND(13) RND(15) RND(26) RND(6)
  x0 += ks2; x1 += k0 + 5u;
#undef RND
}

__device__ __forceinline__ double dsig(double x) { return 0.5 + 0.5 * tanh(0.5 * x); }

// sorted-desc top5 insert; ties -> lower index first (matches lax.top_k)
__device__ __forceinline__ void ins5(double v, int i, double* tv, int* ti) {
  bool beat4 = (v > tv[4]) || (v == tv[4] && i < ti[4]);
  if (!beat4) return;
  tv[4] = v; ti[4] = i;
#pragma unroll
  for (int p = 4; p > 0; --p) {
    bool sw = (tv[p] > tv[p-1]) || (tv[p] == tv[p-1] && ti[p] < ti[p-1]);
    double a0 = sw ? tv[p] : tv[p-1]; double a1 = sw ? tv[p-1] : tv[p];
    tv[p-1] = a0; tv[p] = a1;
    int b0 = sw ? ti[p] : ti[p-1]; int b1 = sw ? ti[p-1] : ti[p];
    ti[p-1] = b0; ti[p] = b1;
  }
}

// exact integer reference D[m][n] for f64 probe: sum_k (4m+k+1)*(16k+n+1)
__device__ __forceinline__ double dref(int m, int n) {
  int s = 0;
#pragma unroll
  for (int k = 0; k < 4; ++k) s += (4*m + k + 1) * (16*k + n + 1);
  return (double)s;
}

// -------- MFMA layout probes: fb[0]=f64 conv (0..3), fb[2]=bf16 maps ok --------
__global__ __launch_bounds__(64) void k_probe(int* __restrict__ fbp) {
  int l = threadIdx.x;
  int lane16 = l & 15, sub = l >> 4;
  {
    double av = (double)(4 * lane16 + sub + 1);     // A[m=lane16][k=sub]
    double bv = (double)(16 * sub + lane16 + 1);    // B[k=sub][n=lane16]
    f64x4 acc = {0., 0., 0., 0.};
    acc = __builtin_amdgcn_mfma_f64_16x16x4f64(av, bv, acc, 0, 0, 0);
    bool o0 = true, o1 = true, o2 = true, o3 = true;
#pragma unroll
    for (int j = 0; j < 4; ++j) {
      double d = acc[j];
      o0 = o0 && (d == dref(4 * sub + j, lane16));
      o1 = o1 && (d == dref(lane16, 4 * sub + j));
      o2 = o2 && (d == dref(sub + 4 * j, lane16));
      o3 = o3 && (d == dref(lane16, sub + 4 * j));
    }
    int a0 = __all(o0), a1 = __all(o1), a2 = __all(o2), a3 = __all(o3);
    if (l == 0) { fbp[0] = a0 ? 0 : a1 ? 1 : a2 ? 2 : 3; fbp[1] = 0; }
  }
  {
    BFrag fa, fbv;
#pragma unroll
    for (int i = 0; i < 8; ++i) {
      int k = sub * 8 + i;
      fa.u[i]  = f2bf((float)((lane16 * 5 + k * 3) % 63 + 1));
      fbv.u[i] = f2bf((float)((k * 7 + lane16 * 11) % 61 + 1));
    }
    f32x4v c = {0.f, 0.f, 0.f, 0.f};
    c = __builtin_amdgcn_mfma_f32_16x16x32_bf16(fa.v, fbv.v, c, 0, 0, 0);
    bool okb = true;
#pragma unroll
    for (int j = 0; j < 4; ++j) {
      int mm = sub * 4 + j, nn = lane16;
      int ref = 0;
      for (int k = 0; k < 32; ++k) ref += ((mm*5 + k*3) % 63 + 1) * ((k*7 + nn*11) % 61 + 1);
      okb = okb && (c[j] == (float)ref);
    }
    int allb = __all(okb);
    if (l == 0) fbp[2] = allb;
  }
}

// -------- one-time: fc_w [k][v] f32 -> whT [v][k] bf16 (tiled transpose) --------
__global__ __launch_bounds__(256) void k_wconv(const float* __restrict__ W, u16* __restrict__ whT) {
  __shared__ u16 tile[64][65];
  int vb = blockIdx.x * 64, kb = blockIdx.y * 64;
  int tid = threadIdx.x;
#pragma unroll
  for (int i = 0; i < 16; ++i) {
    int r = i * 4 + (tid >> 6), c = tid & 63;       // r = k-offset, c = v-offset
    int v = vb + c;
    tile[c][r] = (v < VSZ) ? f2bf(W[(size_t)(kb + r) * VSZ + v]) : (u16)0;
  }
  __syncthreads();
#pragma unroll
  for (int i = 0; i < 16; ++i) {
    int r = i * 4 + (tid >> 6), c = tid & 63;       // r = v-offset, c = k-offset
    int v = vb + r;
    if (v < VSZ) whT[(size_t)v * 1024 + kb + c] = tile[r][c];
  }
}

// -------- fused RNG: gumbel[t][m] for t<80, m<320 --------
__global__ __launch_bounds__(256) void k_rng(double* __restrict__ gum) {
  int idx = blockIdx.x * 256 + threadIdx.x;
  if (idx >= TSZ * 320) return;
  int t = idx / 320, m = idx % 320;
  u32 a0 = 0u, a1 = (u32)t;
  tf2x32(0u, 42u, a0, a1);
  u32 x0 = 0u, x1 = (u32)m;
  tf2x32(a0, a1, x0, x1);
  u32 bits = x0 ^ x1;
  const float TINY = 1.17549435082228750797e-38f;  // 2^-126
  float f = __uint_as_float((bits >> 9) | 0x3f800000u) - 1.0f;
  float u = f + TINY;
  u = fmaxf(TINY, u);
  gum[idx] = -log(-log((double)u));
}

// -------- time encode stage 1 --------
__global__ __launch_bounds__(256) void k_time1(const float* __restrict__ hours, const float* __restrict__ w1,
                                               const float* __restrict__ bb1, double* __restrict__ tp1T) {
  int idx = blockIdx.x * 256 + threadIdx.x;  // 64*1024
  int b = idx & 63, hcol = idx >> 6;
  const float TPO = (float)(2.0 * 3.14159265358979323846 / 24.0);
  float af = hours[b] * TPO;
  double a = (double)af;
  double sv = sin(a), cv = cos(a);
  double vv = tanh(sv * (double)w1[hcol] + cv * (double)w1[HSZ + hcol] + (double)bb1[hcol]);
  tp1T[(size_t)hcol * 64 + b] = vv;
}

// -------- simple split-K gemm (prologue-only, runs once) --------
__global__ __launch_bounds__(256) void k_gemm_simple(const double* __restrict__ XTa, const float* __restrict__ Wa,
                                                     int Ka, int Sa, double* __restrict__ part) {
  int j = blockIdx.x * 256 + threadIdx.x;
  if (j >= GC) return;
  int s = blockIdx.y;
  int kc = Ka / Sa, k0 = s * kc;
  double acc[BSZ];
#pragma unroll
  for (int b = 0; b < BSZ; ++b) acc[b] = 0.0;
  const float* wp = Wa + (size_t)k0 * GC + j;
  const double* xp = XTa + (size_t)k0 * 64;
  for (int k = 0; k < kc; ++k) {
    double wv = (double)wp[0]; wp += GC;
#pragma unroll
    for (int b = 0; b < BSZ; ++b) acc[b] = fma(wv, xp[b], acc[b]);
    xp += 64;
  }
  double* o = part + ((size_t)s * 64) * GC + j;
#pragma unroll
  for (int b = 0; b < BSZ; ++b) o[(size_t)b * GC] = acc[b];
}

// -------- time encode stage 2 reduce --------
__global__ __launch_bounds__(256) void k_t2r(const double* __restrict__ part, const float* __restrict__ b2,
                                             double* __restrict__ h0T, double* __restrict__ c0,
                                             double* __restrict__ h1T, double* __restrict__ c1) {
  int b = blockIdx.y;
  int j = blockIdx.x * 256 + threadIdx.x;
  double acc = (double)b2[j];
  for (int s = 0; s < 8; ++s) acc += part[((size_t)s * 64 + b) * GC + j];
  int l = j >> 11, half = (j >> 10) & 1, hcol = j & 1023;
  if (half == 0) (l ? h1T : h0T)[(size_t)hcol * 64 + b] = acc;
  else           (l ? c1 : c0)[(size_t)b * HSZ + hcol] = acc;
}

// -------- LSTM gemm via f64 MFMA (R8/R13 HW-validated); K=256/slice; part[s][b][col] --------
__global__ __launch_bounds__(256, 4) void k_lstm_mfma(const double* __restrict__ x0, const float* __restrict__ W0,
                                                      const double* __restrict__ x1, const float* __restrict__ W1,
                                                      const double* __restrict__ x2, const float* __restrict__ W2,
                                                      int s1, int s2, double* __restrict__ part,
                                                      const int* __restrict__ fbp) {
  int conv = fbp[0] & 3;
  __shared__ double xs[64 * 64];   // 32KB x-chunk [k][b]
  int tid = threadIdx.x;
  int l = tid & 63, wv = tid >> 6;
  int sub = l >> 4, lane16 = l & 15;
  int colbase = blockIdx.x * 64;
  int s = blockIdx.y;
  const double* XT; const float* W; int k0;
  if (s < s1)      { XT = x0; W = W0; k0 = s * 256; }
  else if (s < s2) { XT = x1; W = W1; k0 = (s - s1) * 256; }
  else             { XT = x2; W = W2; k0 = (s - s2) * 256; }
  int colA = colbase + wv * 16 + lane16;
  f64x4 a0 = {0.,0.,0.,0.}, a1 = {0.,0.,0.,0.}, a2 = {0.,0.,0.,0.}, a3 = {0.,0.,0.,0.};
  const float* wp = W + (size_t)(k0 + sub) * GC + colA;
  float ab[8];
#pragma unroll
  for (int u = 0; u < 8; ++u) { ab[u] = wp[0]; wp += (size_t)4 * GC; }
  for (int ch = 0; ch < 4; ++ch) {
    __syncthreads();
    const double2* src = (const double2*)(XT + (size_t)(k0 + ch * 64) * 64);
    double2* dst = (double2*)xs;
    for (int i = tid; i < 2048; i += 256) dst[i] = src[i];
    __syncthreads();
#pragma unroll
    for (int g = 0; g < 2; ++g) {
#pragma unroll
      for (int u = 0; u < 8; ++u) {
        int ks = g * 8 + u;
        int step = ch * 16 + ks;
        float nv = 0.f;
        if (step + 8 < 64) nv = wp[0];
        wp += (size_t)4 * GC;
        double av = (double)ab[u];
        const double* bp = xs + (ks * 4 + sub) * 64 + lane16;
        double b0 = bp[0], b1 = bp[16], b2 = bp[32], b3 = bp[48];
        a0 = __builtin_amdgcn_mfma_f64_16x16x4f64(av, b0, a0, 0, 0, 0);
        a1 = __builtin_amdgcn_mfma_f64_16x16x4f64(av, b1, a1, 0, 0, 0);
        a2 = __builtin_amdgcn_mfma_f64_16x16x4f64(av, b2, a2, 0, 0, 0);
        a3 = __builtin_amdgcn_mfma_f64_16x16x4f64(av, b3, a3, 0, 0, 0);
        ab[u] = nv;
      }
    }
  }
#pragma unroll
  for (int j = 0; j < 4; ++j) {
    int m = (conv == 0) ? sub * 4 + j : (conv == 2) ? sub + 4 * j : lane16;
    int n = (conv == 0) ? lane16 : (conv == 2) ? lane16 : ((conv == 1) ? sub * 4 + j : sub + 4 * j);
    size_t base = ((size_t)s * 64 + n) * GC + colbase + wv * 16 + m;
    part[base]                   = a0[j];
    part[base + (size_t)16 * GC] = a1[j];
    part[base + (size_t)32 * GC] = a2[j];
    part[base + (size_t)48 * GC] = a3[j];
  }
}

// -------- LSTM cell; optional bf16 emission of h in FC chunk layout [ch][b][k&127] --------
__global__ __launch_bounds__(256) void k_cell(const double* __restrict__ part, int sBeg, int S,
                                              const float* __restrict__ bias,
                                              double* __restrict__ c, double* __restrict__ hT,
                                              int emit, u16* __restrict__ xh) {
  int b = blockIdx.y;
  int hcol = blockIdx.x * 256 + threadIdx.x;
  double gi = (double)bias[hcol];
  double gf = (double)bias[1024 + hcol];
  double gg = (double)bias[2048 + hcol];
  double go = (double)bias[3072 + hcol];
#pragma unroll 4
  for (int s = sBeg; s < sBeg + S; ++s) {
    const double* p = part + ((size_t)s * 64 + b) * GC;
    gi += p[hcol]; gf += p[1024 + hcol]; gg += p[2048 + hcol]; go += p[3072 + hcol];
  }
  size_t ci = (size_t)b * HSZ + hcol;
  double cn = dsig(gf) * c[ci] + dsig(gi) * tanh(gg);
  double hn = dsig(go) * tanh(cn);
  c[ci] = cn;
  hT[(size_t)hcol * 64 + b] = hn;
  if (emit)
    xh[(size_t)(hcol >> 7) * 8192 + (size_t)b * 128 + (hcol & 127)] = f2bf((float)hn);
}

// -------- FC approx via bf16 MFMA (preconverted whT) + per-block top5 --------
__global__ __launch_bounds__(256, 4) void k_fcbf(const u16* __restrict__ xhg, const u16* __restrict__ whT,
                                                 const float* __restrict__ fcb,
                                                 double* __restrict__ candV, int* __restrict__ candI,
                                                 const int* __restrict__ fbp) {
  if (fbp[2] == 0) return;
  __shared__ double xs[64 * 64];     // phase 1: 16KB swizzled xh tile; phase 2: transpose buffer
  u16* lx = (u16*)xs;
  int tid = threadIdx.x;
  int l = tid & 63, wv = tid >> 6;
  int sub = l >> 4, lane16 = l & 15;
  int vbase = blockIdx.x * 64;
  int colA = min(vbase + wv * 16 + lane16, VSZ - 1);
  const u16* wrow = whT + (size_t)colA * 1024;
  f32x4v acc0 = {0,0,0,0}, acc1 = {0,0,0,0}, acc2 = {0,0,0,0}, acc3 = {0,0,0,0};
  for (int ch = 0; ch < 8; ++ch) {
    bf16x8 wh0 = *(const bf16x8*)(wrow + ch * 128 + 0 * 32 + sub * 8);
    bf16x8 wh1 = *(const bf16x8*)(wrow + ch * 128 + 1 * 32 + sub * 8);
    bf16x8 wh2 = *(const bf16x8*)(wrow + ch * 128 + 2 * 32 + sub * 8);
    bf16x8 wh3 = *(const bf16x8*)(wrow + ch * 128 + 3 * 32 + sub * 8);
    __syncthreads();
    {
      const uint4* sg = (const uint4*)(xhg + (size_t)ch * 8192);
      uint4* dl = (uint4*)lx;
#pragma unroll
      for (int i = 0; i < 4; ++i) {
        int u = tid + i * 256;               // unit = b*16 + g (g = k'/8)
        int bswz = u >> 4, g = u & 15;
        dl[(bswz << 4) | (g ^ (bswz & 7))] = sg[u];  // XOR-swizzle kills bank conflicts
      }
    }
    __syncthreads();
#pragma unroll
    for (int kt = 0; kt < 4; ++kt) {
      bf16x8 whv = (kt == 0) ? wh0 : (kt == 1) ? wh1 : (kt == 2) ? wh2 : wh3;
#define BT_STEP(BT, ACC) {                                                              \
        int bb = BT * 16 + lane16;                                                      \
        const bf16x8* bp2 = (const bf16x8*)lx + ((bb << 4) | ((kt * 4 + sub) ^ (bb & 7))); \
        ACC = __builtin_amdgcn_mfma_f32_16x16x32_bf16(whv, *bp2, ACC, 0, 0, 0); }
      BT_STEP(0, acc0)
      BT_STEP(1, acc1)
      BT_STEP(2, acc2)
      BT_STEP(3, acc3)
#undef BT_STEP
    }
  }
  __syncthreads();   // staging reads done; reuse xs as transpose buffer
  // D: m=(l>>4)*4+j (vocab), n=lane16 (+bt*16) (batch)  [probe-verified, R11/R13-validated]
#pragma unroll
  for (int j = 0; j < 4; ++j) {
    int vl = wv * 16 + sub * 4 + j;
    int v = vbase + vl;
    bool okv = (v < VSZ);
    double bi = okv ? (double)fcb[min(v, VSZ - 1)] : 0.0;
    int b0i = lane16, b1i = 16 + lane16, b2i = 32 + lane16, b3i = 48 + lane16;
    xs[b0i * 64 + ((vl + b0i) & 63)] = okv ? ((double)acc0[j] + bi) / 0.75 : -INFINITY;
    xs[b1i * 64 + ((vl + b1i) & 63)] = okv ? ((double)acc1[j] + bi) / 0.75 : -INFINITY;
    xs[b2i * 64 + ((vl + b2i) & 63)] = okv ? ((double)acc2[j] + bi) / 0.75 : -INFINITY;
    xs[b3i * 64 + ((vl + b3i) & 63)] = okv ? ((double)acc3[j] + bi) / 0.75 : -INFINITY;
  }
  __syncthreads();
  if (tid < 64) {
    int b = tid;
    double tv[5]; int ti[5];
#pragma unroll
    for (int p = 0; p < 5; ++p) { tv[p] = -INFINITY; ti[p] = INT_MAX; }
    for (int vl2 = 0; vl2 < 64; ++vl2)
      ins5(xs[b * 64 + ((vl2 + b) & 63)], vbase + vl2, tv, ti);
#pragma unroll
    for (int r = 0; r < 5; ++r) {
      candV[(size_t)b * NCAND + blockIdx.x * 5 + r] = tv[r];
      candI[(size_t)b * NCAND + blockIdx.x * 5 + r] = ti[r];
    }
  }
}

// -------- FC via f64 MFMA (launched only when ws too small for whT) --------
__global__ __launch_bounds__(256, 4) void k_fcf64(const double* __restrict__ h1T, const float* __restrict__ W,
                                                  const float* __restrict__ fcb,
                                                  double* __restrict__ candV, int* __restrict__ candI,
                                                  const int* __restrict__ fbp) {
  int conv = fbp[0] & 3;
  __shared__ double xs[64 * 64];
  int tid = threadIdx.x;
  int l = tid & 63, wv = tid >> 6;
  int sub = l >> 4, lane16 = l & 15;
  int vbase = blockIdx.x * 64;
  int colA = min(vbase + wv * 16 + lane16, VSZ - 1);
  f64x4 a0 = {0.,0.,0.,0.}, a1 = {0.,0.,0.,0.}, a2 = {0.,0.,0.,0.}, a3 = {0.,0.,0.,0.};
  const float* wp = W + (size_t)sub * VSZ + colA;
  float ab[8];
#pragma unroll
  for (int u = 0; u < 8; ++u) { ab[u] = wp[0]; wp += (size_t)4 * VSZ; }
  for (int ch = 0; ch < 16; ++ch) {
    __syncthreads();
    const double2* src = (const double2*)(h1T + (size_t)ch * 64 * 64);
    double2* dst = (double2*)xs;
    for (int i = tid; i < 2048; i += 256) dst[i] = src[i];
    __syncthreads();
#pragma unroll
    for (int g = 0; g < 2; ++g) {
#pragma unroll
      for (int u = 0; u < 8; ++u) {
        int ks = g * 8 + u;
        int step = ch * 16 + ks;
        float nv = 0.f;
        if (step + 8 < 256) nv = wp[0];
        wp += (size_t)4 * VSZ;
        double av = (double)ab[u];
        const double* bp = xs + (ks * 4 + sub) * 64 + lane16;
        double b0 = bp[0], b1 = bp[16], b2 = bp[32], b3 = bp[48];
        a0 = __builtin_amdgcn_mfma_f64_16x16x4f64(av, b0, a0, 0, 0, 0);
        a1 = __builtin_amdgcn_mfma_f64_16x16x4f64(av, b1, a1, 0, 0, 0);
        a2 = __builtin_amdgcn_mfma_f64_16x16x4f64(av, b2, a2, 0, 0, 0);
        a3 = __builtin_amdgcn_mfma_f64_16x16x4f64(av, b3, a3, 0, 0, 0);
        ab[u] = nv;
      }
    }
  }
  __syncthreads();
#pragma unroll
  for (int j = 0; j < 4; ++j) {
    int m = (conv == 0) ? sub * 4 + j : (conv == 2) ? sub + 4 * j : lane16;
    int n = (conv == 0) ? lane16 : (conv == 2) ? lane16 : ((conv == 1) ? sub * 4 + j : sub + 4 * j);
    int vl = wv * 16 + m;
    int v = vbase + vl;
    bool okv = (v < VSZ);
    double bi = okv ? (double)fcb[min(v, VSZ - 1)] : 0.0;
    int b0i = n, b1i = 16 + n, b2i = 32 + n, b3i = 48 + n;
    xs[b0i * 64 + ((vl + b0i) & 63)] = okv ? (a0[j] + bi) / 0.75 : -INFINITY;
    xs[b1i * 64 + ((vl + b1i) & 63)] = okv ? (a1[j] + bi) / 0.75 : -INFINITY;
    xs[b2i * 64 + ((vl + b2i) & 63)] = okv ? (a2[j] + bi) / 0.75 : -INFINITY;
    xs[b3i * 64 + ((vl + b3i) & 63)] = okv ? (a3[j] + bi) / 0.75 : -INFINITY;
  }
  __syncthreads();
  if (tid < 64) {
    int b = tid;
    double tv[5]; int ti[5];
#pragma unroll
    for (int p = 0; p < 5; ++p) { tv[p] = -INFINITY; ti[p] = INT_MAX; }
    for (int vl2 = 0; vl2 < 64; ++vl2)
      ins5(xs[b * 64 + ((vl2 + b) & 63)], vbase + vl2, tv, ti);
#pragma unroll
    for (int r = 0; r < 5; ++r) {
      candV[(size_t)b * NCAND + blockIdx.x * 5 + r] = tv[r];
      candI[(size_t)b * NCAND + blockIdx.x * 5 + r] = ti[r];
    }
  }
}

// -------- refine + finalize: approx top-16 -> exact f64 logits -> top5/gumbel/probs --------
__global__ __launch_bounds__(256) void k_rfin(const double* __restrict__ candV, const int* __restrict__ candI,
                                              const float* __restrict__ W, const float* __restrict__ fcb,
                                              const double* __restrict__ h1T,
                                              const double* __restrict__ gum, int t,
                                              const float* __restrict__ embed,
                                              float* __restrict__ out, double* __restrict__ xt0) {
  __shared__ float sv[NCAND];
  __shared__ int   si[NCAND];
  __shared__ double exS[NREF];
  __shared__ float wvv[4]; __shared__ int wvi[4]; __shared__ int wvs[4];
  int b = blockIdx.x, tid = threadIdx.x;
  int l = tid & 63, wvd = tid >> 6;
  for (int e = tid; e < NCAND; e += 256) {
    sv[e] = (float)candV[(size_t)b * NCAND + e];
    si[e] = candI[(size_t)b * NCAND + e];
  }
  __syncthreads();
  int cidx[NREF];
#pragma unroll
  for (int r = 0; r < NREF; ++r) {
    float bv = -INFINITY; int bi = INT_MAX, bs = 0;
    for (int e = tid; e < NCAND; e += 256) {
      float v = sv[e]; int i2 = si[e];
      if (v > bv || (v == bv && i2 < bi)) { bv = v; bi = i2; bs = e; }
    }
#pragma unroll
    for (int off = 1; off < 64; off <<= 1) {
      float ov = __shfl_xor(bv, off, 64);
      int oi = __shfl_xor(bi, off, 64);
      int os = __shfl_xor(bs, off, 64);
      if (ov > bv || (ov == bv && oi < bi)) { bv = ov; bi = oi; bs = os; }
    }
    if (l == 0) { wvv[wvd] = bv; wvi[wvd] = bi; wvs[wvd] = bs; }
    __syncthreads();
    float fv = wvv[0]; int fi = wvi[0], fs = wvs[0];
#pragma unroll
    for (int q = 1; q < 4; ++q) {
      float ov = wvv[q]; int oi = wvi[q], os = wvs[q];
      if (ov > fv || (ov == fv && oi < fi)) { fv = ov; fi = oi; fs = os; }
    }
    cidx[r] = fi;
    __syncthreads();
    if (tid == 0) sv[fs] = -INFINITY;
    __syncthreads();
  }
  // exact dots: wave wvd handles candidates wvd, wvd+4, wvd+8, wvd+12 (no block barriers)
#pragma unroll
  for (int rr = 0; rr < 4; ++rr) {
    int c = wvd + rr * 4;
    int vc = cidx[c];
    double p = 0.0;
#pragma unroll
    for (int i = 0; i < 16; ++i) {
      int k = i * 64 + l;
      p = fma((double)W[(size_t)k * VSZ + vc], h1T[(size_t)k * 64 + b], p);
    }
#pragma unroll
    for (int off = 1; off < 64; off <<= 1) p += __shfl_xor(p, off, 64);
    if (l == 0) exS[c] = (p + (double)fcb[vc]) / 0.75;
  }
  __syncthreads();
  double tv[5]; int ti[5];
#pragma unroll
  for (int p = 0; p < 5; ++p) { tv[p] = -INFINITY; ti[p] = INT_MAX; }
#pragma unroll
  for (int c = 0; c < NREF; ++c) ins5(exS[c], cidx[c], tv, ti);
  const double* g = gum + (size_t)t * 320 + b * 5;
  double bestv = tv[0] + g[0]; int best = 0;
#pragma unroll
  for (int k2 = 1; k2 < 5; ++k2) { double vv2 = tv[k2] + g[k2]; if (vv2 > bestv) { bestv = vv2; best = k2; } }
  int nxt = ti[best];
  if (tid == 0) {
    out[b * TSZ + t] = (float)nxt;
    double m = tv[0];
    double exx[5]; double s = 0.0;
#pragma unroll
    for (int k2 = 0; k2 < 5; ++k2) { exx[k2] = exp(tv[k2] - m); s += exx[k2]; }
    float* po = out + BSZ * TSZ + ((size_t)b * TSZ + t) * 5;
#pragma unroll
    for (int k2 = 0; k2 < 5; ++k2) po[k2] = (float)(exx[k2] / s);
  }
  xt0[(size_t)tid * 64 + b] = (double)embed[(size_t)nxt * ESZ + tid];
}

// -------- initial embedding of SOS --------
__global__ __launch_bounds__(256) void k_emb0(const float* __restrict__ embed, const int* __restrict__ sos,
                                              double* __restrict__ xt0) {
  int idx = blockIdx.x * 256 + threadIdx.x;
  int b = idx & 63, k = idx >> 6;
  xt0[(size_t)k * 64 + b] = (double)embed[(size_t)sos[0] * ESZ + k];
}

extern "C" void kernel_launch(void* const* d_in, const int* in_sizes, int n_in,
                              void* d_out, int out_size, void* d_ws, size_t ws_size,
                              hipStream_t stream) {
  const float* hours = (const float*)d_in[0];
  const float* tp_w1 = (const float*)d_in[1];
  const float* tp_b1 = (const float*)d_in[2];
  const float* tp_w2 = (const float*)d_in[3];
  const float* tp_b2 = (const float*)d_in[4];
  const float* embed = (const float*)d_in[5];
  const float* w_ih0 = (const float*)d_in[6];
  const float* w_hh0 = (const float*)d_in[7];
  const float* b0    = (const float*)d_in[8];
  const float* w_ih1 = (const float*)d_in[9];
  const float* w_hh1 = (const float*)d_in[10];
  const float* b1    = (const float*)d_in[11];
  const float* fc_w  = (const float*)d_in[12];
  const float* fc_b  = (const float*)d_in[13];
  const int*   sos   = (const int*)d_in[14];
  float* out = (float*)d_out;

  char* w = (char*)d_ws;
  double* part = (double*)w;  w += (size_t)NSLOT * 64 * GC * 8;   // 27.3 MB lstm partials
  double* xt0  = (double*)w;  w += (size_t)ESZ * 64 * 8;
  double* h0T  = (double*)w;  w += (size_t)HSZ * 64 * 8;
  double* h1T  = (double*)w;  w += (size_t)HSZ * 64 * 8;
  double* c0   = (double*)w;  w += (size_t)BSZ * HSZ * 8;
  double* c1   = (double*)w;  w += (size_t)BSZ * HSZ * 8;
  double* tp1T = (double*)w;  w += (size_t)HSZ * 64 * 8;
  double* gum  = (double*)w;  w += (size_t)TSZ * 320 * 8;
  double* candV = (double*)w; w += (size_t)BSZ * NCAND * 8;       // 2.01 MB, b-major
  int*    candI = (int*)w;    w += (size_t)BSZ * NCAND * 4;       // 1.01 MB
  int*    fbuf  = (int*)w;    w += 64;                            // [0]=f64 conv, [2]=bf16 ok
  u16*    xhg   = (u16*)w;    w += (size_t)HSZ * 64 * 2;          // 128 KB bf16 h1 (chunk layout)
  u16*    whT   = (u16*)w;    w += (size_t)VSZ * 1024 * 2;        // 102.9 MB transposed bf16 fc_w
  size_t need = (size_t)(w - (char*)d_ws);
  int useBF = (ws_size >= need) ? 1 : 0;

  k_probe<<<dim3(1), dim3(64), 0, stream>>>(fbuf);
  k_rng<<<dim3(100), dim3(256), 0, stream>>>(gum);
  k_time1<<<dim3(256), dim3(256), 0, stream>>>(hours, tp_w1, tp_b1, tp1T);
  k_gemm_simple<<<dim3(16, 8), dim3(256), 0, stream>>>(tp1T, tp_w2, 1024, 8, part);
  k_t2r<<<dim3(16, 64), dim3(256), 0, stream>>>(part, tp_b2, h0T, c0, h1T, c1);
  k_emb0<<<dim3(64), dim3(256), 0, stream>>>(embed, sos, xt0);
  if (useBF)
    k_wconv<<<dim3(786, 16), dim3(256), 0, stream>>>(fc_w, whT);

  double* part9 = part + (size_t)9 * 64 * GC;
  for (int t = 0; t < TSZ; ++t) {
    // A: slot 0 = xt0*w_ih0 (K=256), slots 1-4 = h0*w_hh0, slots 5-8 = h1*w_hh1
    k_lstm_mfma<<<dim3(64, 9), dim3(256), 0, stream>>>(xt0, w_ih0, h0T, w_hh0, h1T, w_hh1, 1, 5, part, fbuf);
    // layer-0 cell: slots 0..4
    k_cell<<<dim3(4, 64), dim3(256), 0, stream>>>(part, 0, 5, b0, c0, h0T, 0, xhg);
    // B: slices 0-3 = h0n*w_ih1 -> slots 9..12
    k_lstm_mfma<<<dim3(64, 4), dim3(256), 0, stream>>>(h0T, w_ih1, h0T, w_ih1, h0T, w_ih1, 4, 4, part9, fbuf);
    // layer-1 cell: slots 5..12 = h1*w_hh1 (5-8) + h0n*w_ih1 (9-12)
    k_cell<<<dim3(4, 64), dim3(256), 0, stream>>>(part, 5, 8, b1, c1, h1T, 1, xhg);
    if (useBF)
      k_fcbf<<<dim3(NFCB), dim3(256), 0, stream>>>(xhg, whT, fc_b, candV, candI, fbuf);
    else
      k_fcf64<<<dim3(NFCB), dim3(256), 0, stream>>>(h1T, fc_w, fc_b, candV, candI, fbuf);
    k_rfin<<<dim3(64), dim3(256), 0, stream>>>(candV, candI, fc_w, fc_b, h1T, gum, t, embed, out, xt0);
  }
}